// Round 4
// baseline (1454.245 us; speedup 1.0000x reference)
//
#include <hip/hip_runtime.h>

#define BT   (512*256)
// hbuf (bytes): zeros @0..127, pad, h @192..319  (==64 mod 128: h line banks
// 16-31 for a0 / 0-15 for a1, opposite zero-lane banks -> max 2-way, free)
#define HB0b 192
#define HLENb 320
#define LOG2E 1.44269504088896f

using short8  = __attribute__((ext_vector_type(8))) short;
using floatx4 = __attribute__((ext_vector_type(4))) float;
using int4v   = __attribute__((ext_vector_type(4))) int;
using ushort4v= __attribute__((ext_vector_type(4))) unsigned short;

__device__ inline unsigned short f2bf(float f){
  unsigned int u = __float_as_uint(f);
  u += 0x7FFFu + ((u >> 16) & 1u);          // RNE
  return (unsigned short)(u >> 16);
}
__device__ inline float bf2f(unsigned short u){
  return __uint_as_float(((unsigned int)u) << 16);
}
__device__ inline float rcpf(float x){ return __builtin_amdgcn_rcpf(x); }
__device__ inline float ex2(float x){ return __builtin_amdgcn_exp2f(x); }

// 512 blocks x 512 threads, ONE batch per block, 2 blocks/CU (4 waves/SIMD
// from two INDEPENDENTLY-barriered workgroups -> anti-phase latency fill).
// Round-3 post-mortem: occupancy engaged (41.5%) but persistent regs (wq32+
// xfr16+fq8+xvp16+transients) blew the 128-total cap -> 54MB/dispatch scratch
// spills. This round: xfr (W_ih bf16) and fq (fc1 i8) are used ONCE per outer
// iter -> staged in LDS at init (each thread writes the exact 16B it reads
// back at tid*16: coalesced, conflict-free, producer==consumer) and reloaded
// per outer. -24 persistent VGPRs; wq stays in regs (inner-loop critical).
// LDS 58KB/block, 2 blocks = 116KB < 160KB.
__global__ __launch_bounds__(512,4) void k_seq(
    const float* __restrict__ in,
    const float* __restrict__ Wih,  const float* __restrict__ Whh,
    const float* __restrict__ bih,  const float* __restrict__ bhh,
    const float* __restrict__ fc1w, const float* __restrict__ fc1b,
    const float* __restrict__ fc2w, const float* __restrict__ fc2b,
    const float* __restrict__ i1w,  const float* __restrict__ i1b,
    const float* __restrict__ i3w,  const float* __restrict__ i3b,
    const float* __restrict__ scw,  const float* __restrict__ zonew,
    float* __restrict__ out)
{
  __shared__ __align__(16) signed char hbuf[2][HLENb];     // i8 h + zero region
  __shared__ __align__(16) float scratch[640];             // int-module weights
  __shared__ __align__(8)  unsigned short toutl[256];      // bf16 TOut history
  __shared__ __align__(8)  unsigned short extl[256];       // bf16 Ext results
  __shared__ __align__(16) unsigned short exl[1024];       // bf16 Ext_X cols [t][4]
  __shared__ float t0l[256];                               // T0 f32
  __shared__ float hvitl[256];                             // HVAC + int_all f32
  __shared__ __align__(16) float parts[8];                 // fc2 wave partials
  __shared__ __align__(16) unsigned short wihl[16384];     // W_ih bf16 staged [g][tid*8]
  __shared__ __align__(16) signed char fcl[16384];         // fc1 i8 staged [c][tid*16]

  const int tid = threadIdx.x;
  const int wv  = tid >> 6;             // 0..7
  const int ln  = tid & 63;
  const int l15 = ln & 15;
  const int quad= ln >> 4;
  const int bb  = blockIdx.x;           // == batch index

  // ---- init: stage per-block tables ----
  if(tid<256){
    const float* row = in + bb*1792 + tid*7;
    t0l[tid] = row[0];
    exl[tid*4+0]=f2bf(row[1]); exl[tid*4+1]=f2bf(row[2]);
    exl[tid*4+2]=f2bf(row[3]); exl[tid*4+3]=f2bf(row[4]);
  }
  for(int p=tid; p<2*HLENb; p+=512) ((signed char*)hbuf)[p]=0;
  if(tid<8) toutl[tid] = f2bf(in[bb*1792+tid*7]);
  float* lw4 = scratch;
  float* l3  = scratch + 512;
  if(tid>=256 && tid<384){
    int j=tid-256;
    lw4[j*4+0]=i1w[j*3+0]; lw4[j*4+1]=i1w[j*3+1];
    lw4[j*4+2]=i1w[j*3+2]; lw4[j*4+3]=i1b[j];
    l3[j]=i3w[j];
  }
  __syncthreads();
  if(tid<128) hbuf[0][HB0b+tid] = 127;   // h=1.0 -> q=127

  // ---- fused int module (one t per thread, tid<256) ----
  if(tid<256){
    const float b30=i3b[0], sc0=scw[0];
    int t=tid;
    const float* row = in + bb*1792 + t*7;
    float x0=row[3],x1=row[4],x2=row[5], acc=0.f;
    #pragma unroll 8
    for(int j=0;j<128;j++){
      float r=fmaxf(lw4[j*4]*x0+lw4[j*4+1]*x1+lw4[j*4+2]*x2+lw4[j*4+3],0.f);
      acc += r*l3[j];
    }
    float v = rcpf(1.f+__expf(-(acc+b30)))*sc0;
    float itv = (t<8)?0.f:v;
    hvitl[t] = row[6] + itv;
    out[3*BT+bb*256+t]=itv;              // Int_list
    out[BT+bb*256+t]=row[6];             // HVAC_list
    if(t<8){ out[bb*256+t]=row[0]; out[2*BT+bb*256+t]=0.f; }
  }

  // ---- i8 weight quantization (per-row scale): wq in regs, xfr/fq -> LDS ----
  int4v wq[4][2];        // [gate][K-chunk], rows n = 128g + 16wv + l15
  float dq[4];
  float bsum[4];
  #pragma unroll
  for(int g=0;g<4;g++){
    int n = 128*g + 16*wv + l15;
    bsum[g] = (bih[n]+bhh[n])*LOG2E;
    const float* wr = Whh + n*128;
    float mx = 1e-20f;
    for(int j=0;j<128;j++) mx = fmaxf(mx, fabsf(wr[j]));
    float qs = 127.f/mx;
    dq[g] = mx * (LOG2E/16129.f);        // log2e/127^2
    #pragma unroll
    for(int c=0;c<2;c++){
      int4v v4;
      #pragma unroll
      for(int d=0;d<4;d++){
        int pk=0;
        #pragma unroll
        for(int bq=0;bq<4;bq++){
          int kk = c*64 + quad*16 + d*4 + bq;
          int q = __float2int_rn(wr[kk]*qs);
          pk |= (q & 255) << (8*bq);
        }
        v4[d]=pk;
      }
      wq[g][c]=v4;
    }
    short8 f;
    #pragma unroll
    for(int j=0;j<8;j++){ int kk=quad*8+j; f[j]=(short)f2bf(kk<5?Wih[n*5+kk]*LOG2E:0.f); }
    *(short8*)&wihl[g*4096 + tid*8] = f;       // staged: read back at same addr
  }
  float dqf;                             // fc1 i8 (NOT log2e-scaled), row n2 = 16wv + l15
  {
    int n2 = 16*wv + l15;
    const float* fr = fc1w + n2*128;
    float mx = 1e-20f;
    for(int j=0;j<128;j++) mx = fmaxf(mx, fabsf(fr[j]));
    float qs = 127.f/mx;
    dqf = mx * (1.f/16129.f);
    #pragma unroll
    for(int c=0;c<2;c++){
      int4v v4;
      #pragma unroll
      for(int d=0;d<4;d++){
        int pk=0;
        #pragma unroll
        for(int bq=0;bq<4;bq++){
          int kk = c*64 + quad*16 + d*4 + bq;
          int q = __float2int_rn(fr[kk]*qs);
          pk |= (q & 255) << (8*bq);
        }
        v4[d]=pk;
      }
      *(int4v*)&fcl[c*8192 + tid*16] = v4;     // staged: read back at same addr
    }
  }

  // ---- per-lane persistent scalars ----
  const int  u     = 16*wv + l15;           // this lane's unit
  const int  arow  = ((l15&3)==0) ? HB0b : 0;   // rows 0,4,8,12 = batch; else zero
  const int  aoff  = arow + quad*16;
  const int  hwoff = HB0b + u;
  const int  bpa0  = l15<<2;                // bpermute byte addr, k<4 (rows 0-3)
  const int  bpa1  = bpa0 + 64;             // k>=4 (rows 4-7, lanes 16-31)
  const float fb    = fc1b[u];
  const float fcw_u = fc2w[u];
  const float fc2b0 = fc2b[0];
  const float zwv   = zonew[0];
  const floatx4 ZV  = {0.f,0.f,0.f,0.f};
  const int4v   ZI  = {0,0,0,0};
  const short8  Z8  = 0;
  float E0 = in[bb*1792 + 56];              // E in EVERY lane's registers
  float c0 = 1.f;
  __syncthreads();                          // covers wihl/fcl staging too

  #pragma unroll 1
  for(int i=8;i<256;i++){
    // ===== phase A: deferred E-update (i-1), TOut, embed, x-MFMA+pack+bpermute =====
    if(i>8){
      floatx4 pa=*(const floatx4*)&parts[0];
      floatx4 pb=*(const floatx4*)&parts[4];
      float ext0=((pa[0]+pa[1])+(pa[2]+pa[3]))+((pb[0]+pb[1])+(pb[2]+pb[3]))+fc2b0;
      int ip = i-1;
      float tot0 = ext0 + hvitl[ip];
      if(ip<128){
        float ratio=(float)ip*0.0078125f;
        E0 = ratio*t0l[ip] + (1.f-ratio)*E0 + tot0*zwv;
      } else {
        E0 += tot0*zwv;
      }
      if(tid==0) extl[ip]=f2bf(ext0);
    }
    if(tid==0) toutl[i]=f2bf(E0);            // TOut[:,i]=E
    int xvp[8][2];                           // packed bf16 x-gate pairs: [k][{i|f, g|o}]
    {
      short8 ea = Z8;
      if(ln<8){                              // rows 0-7 = window slots
        int p=i-7+ln;
        float tos = (p==i) ? E0 : bf2f(toutl[p]);
        float tmix;
        if(i<128){
          float ratio=(float)i*0.0078125f;
          tmix = t0l[p]*ratio + tos*(1.f-ratio);
        } else tmix = tos;
        ea[0]=(short)f2bf(tmix);
        ushort4v e4 = *(const ushort4v*)&exl[p*4];
        ea[1]=(short)e4[0]; ea[2]=(short)e4[1];
        ea[3]=(short)e4[2]; ea[4]=(short)e4[3];
      }
      #pragma unroll
      for(int gp=0; gp<2; gp++){             // gate pairs (i,f) and (g,o)
        short8 xf0 = *(const short8*)&wihl[(2*gp  )*4096 + tid*8];
        short8 xf1 = *(const short8*)&wihl[(2*gp+1)*4096 + tid*8];
        floatx4 zl=__builtin_amdgcn_mfma_f32_16x16x32_bf16(ea, xf0, ZV,0,0,0);
        floatx4 zh=__builtin_amdgcn_mfma_f32_16x16x32_bf16(ea, xf1, ZV,0,0,0);
        #pragma unroll
        for(int r=0;r<4;r++){
          float lo = zl[r]+bsum[2*gp];
          float hi = zh[r]+bsum[2*gp+1];
          int pk;
          asm("v_cvt_pk_bf16_f32 %0, %1, %2" : "=v"(pk) : "v"(lo), "v"(hi));
          xvp[r][gp]   = __builtin_amdgcn_ds_bpermute(bpa0, pk);  // row r   (k=r)
          xvp[r+4][gp] = __builtin_amdgcn_ds_bpermute(bpa1, pk);  // row r+4 (k=r+4)
        }
      }
    }
    // NO barrier here: hbuf/parts already fenced by prev iter's barriers.

    // ===== 8 inner LSTM steps: 8 i8 MFMAs/wave, single nonlin chain =====
    #pragma unroll
    for(int k=0;k<8;k++){
      const signed char* hb = &hbuf[k&1][0];
      int4v a0 = *(const int4v*)(hb + aoff);        // K 0..63
      int4v a1 = *(const int4v*)(hb + aoff + 64);   // K 64..127
      int accs[4];
      #pragma unroll
      for(int g=0;g<4;g++){
        int4v za = __builtin_amdgcn_mfma_i32_16x16x64_i8(a0, wq[g][0], ZI,0,0,0);
        int4v zb = __builtin_amdgcn_mfma_i32_16x16x64_i8(a1, wq[g][1], ZI,0,0,0);
        accs[g] = za[0]+zb[0];                      // independent MFMAs, 1 add
      }
      int p0=xvp[k][0], p1=xvp[k][1];
      float xi = __uint_as_float(((unsigned)p0)<<16);
      float xf = __uint_as_float((unsigned)p0 & 0xffff0000u);
      float xgg= __uint_as_float(((unsigned)p1)<<16);
      float xo = __uint_as_float((unsigned)p1 & 0xffff0000u);
      float gi=fmaf((float)accs[0],dq[0],xi);       // all in log2e domain
      float gf=fmaf((float)accs[1],dq[1],xf);
      float gg=fmaf((float)accs[2],dq[2],xgg);
      float go=fmaf((float)accs[3],dq[3],xo);
      float ef =ex2(-gf);                           // bare v_exp
      float egi=ex2(-gi);
      float egg=ex2(-2.f*gg);
      float sf = rcpf(1.f+ef);
      float itn=(1.f-egg)*rcpf((1.f+egi)*(1.f+egg));
      c0 = sf*c0 + itn;
      float ego=ex2(-go);
      float ec =ex2(-2.8853900818f*c0);             // c unscaled: x2log2e
      float hv2=(1.f-ec)*rcpf((1.f+ego)*(1.f+ec));
      int q = __float2int_rn(hv2*127.f);            // |h|<1 -> |q|<=127
      hbuf[(k+1)&1][hwoff] = (signed char)q;        // quads 1-3 dup same value
      __syncthreads();
    }

    // ===== fc1 (i8, weights from LDS) + within-quad fc2 reduce =====
    {
      const signed char* hb = &hbuf[0][0];
      int4v a0 = *(const int4v*)(hb + aoff);
      int4v a1 = *(const int4v*)(hb + aoff + 64);
      int4v w0 = *(const int4v*)&fcl[tid*16];
      int4v w1 = *(const int4v*)&fcl[8192 + tid*16];
      int4v za = __builtin_amdgcn_mfma_i32_16x16x64_i8(a0, w0, ZI,0,0,0);
      int4v zb = __builtin_amdgcn_mfma_i32_16x16x64_i8(a1, w1, ZI,0,0,0);
      float fv = (float)(za[0]+zb[0])*dqf + fb;
      float pv = fmaxf(fv,0.f)*fcw_u;
      pv += __shfl_xor(pv, 1, 64);       // xor{1,2,4,8} stays within quad
      pv += __shfl_xor(pv, 2, 64);
      pv += __shfl_xor(pv, 4, 64);
      pv += __shfl_xor(pv, 8, 64);
      if(ln==0) parts[wv] = pv;          // quads 1-3 dup discarded
    }
    __syncthreads();
  }

  // ===== tail: ext(255) from last fc =====
  if(tid==0){
    float ext0 = ((parts[0]+parts[1])+(parts[2]+parts[3]))
               + ((parts[4]+parts[5])+(parts[6]+parts[7])) + fc2b0;
    extl[255]=f2bf(ext0);
  }
  __syncthreads();

  // ===== flush TOut / Ext_list from LDS =====
  if(tid<248){
    int i2 = tid + 8;
    out[bb*256+i2]      = bf2f(toutl[i2]);
    out[2*BT+bb*256+i2] = bf2f(extl[i2]);
  }
}

extern "C" void kernel_launch(void* const* d_in, const int* in_sizes, int n_in,
                              void* d_out, int out_size, void* d_ws, size_t ws_size,
                              hipStream_t stream)
{
  const float* in   = (const float*)d_in[0];
  const float* Wih  = (const float*)d_in[1];
  const float* Whh  = (const float*)d_in[2];
  const float* bih  = (const float*)d_in[3];
  const float* bhh  = (const float*)d_in[4];
  const float* fc1w = (const float*)d_in[5];
  const float* fc1b = (const float*)d_in[6];
  const float* fc2w = (const float*)d_in[7];
  const float* fc2b = (const float*)d_in[8];
  const float* i1w  = (const float*)d_in[9];
  const float* i1b  = (const float*)d_in[10];
  const float* i3w  = (const float*)d_in[11];
  const float* i3b  = (const float*)d_in[12];
  const float* scw  = (const float*)d_in[13];
  const float* zw   = (const float*)d_in[14];
  float* out = (float*)d_out;

  k_seq<<<dim3(512), dim3(512), 0, stream>>>(in, Wih, Whh, bih, bhh,
                                             fc1w, fc1b, fc2w, fc2b,
                                             i1w, i1b, i3w, i3b, scw, zw, out);
}

// Round 6
// 1109.033 us; speedup vs baseline: 1.3113x; 1.3113x over previous
//
#include <hip/hip_runtime.h>

#define BT   (512*256)
// hbuf (bytes): zeros @0..127, pad, b0 h @192..319, b1 h @320..447
// HB0b/HB1b ==64 (mod 128): h lines on banks 16-31 for a0 / 0-15 for a1,
// opposite the zero-lane banks -> max 2-way (free).
#define HB0b 192
#define HB1b 320
#define HLENb 448
#define LOG2E 1.44269504088896f

using short8  = __attribute__((ext_vector_type(8))) short;
using floatx4 = __attribute__((ext_vector_type(4))) float;
using int4v   = __attribute__((ext_vector_type(4))) int;
using ushort4v= __attribute__((ext_vector_type(4))) unsigned short;

__device__ inline unsigned short f2bf(float f){
  unsigned int u = __float_as_uint(f);
  u += 0x7FFFu + ((u >> 16) & 1u);          // RNE
  return (unsigned short)(u >> 16);
}
__device__ inline float bf2f(unsigned short u){
  return __uint_as_float(((unsigned int)u) << 16);
}
__device__ inline float rcpf(float x){ return __builtin_amdgcn_rcpf(x); }
__device__ inline float ex2(float x){ return __builtin_amdgcn_exp2f(x); }

// 256 blocks x 512 threads (round-1 969us base). SOFTWARE-PIPELINED PHASE A:
// the x-gate MFMA is linear in the embed; only window slot 7 (fresh E(i))
// depends on the preceding fc. The bulk of xv(i+1) (embed build, 4 bf16
// MFMAs, 32 bpermutes) is computed during iter i -- slot 6 uses the E
// register every lane holds, slots 0-5 read old toutl, slot 7 prepared with
// its known t0*ratio part -- and phase A(i+1) applies a 4-fma rank-1
// correction xv[7][g] += kappa*E*Wih[n,0]*log2e (kappa=1-ratio, 1 for
// i>=128). k=0's hbuf reads hoisted above the bulk so latencies mutually
// hide. ROUND-5 BUGFIX: parts layout unified to CONTIGUOUS (parts[0..7]=
// batch0, parts[8..15]=batch1) across fc-write / phase-A read / tail --
// round 5 wrote interleaved but read contiguous, mixing batches.
__global__ __launch_bounds__(512,1) void k_seq(
    const float* __restrict__ in,
    const float* __restrict__ Wih,  const float* __restrict__ Whh,
    const float* __restrict__ bih,  const float* __restrict__ bhh,
    const float* __restrict__ fc1w, const float* __restrict__ fc1b,
    const float* __restrict__ fc2w, const float* __restrict__ fc2b,
    const float* __restrict__ i1w,  const float* __restrict__ i1b,
    const float* __restrict__ i3w,  const float* __restrict__ i3b,
    const float* __restrict__ scw,  const float* __restrict__ zonew,
    float* __restrict__ out)
{
  __shared__ __align__(16) signed char hbuf[2][HLENb];     // i8 h + zero region
  __shared__ __align__(16) float scratch[640];             // int-module weights
  __shared__ __align__(8)  unsigned short toutl[512];      // bf16 TOut history [b][256]
  __shared__ __align__(8)  unsigned short extl[512];       // bf16 Ext results [b][256]
  __shared__ __align__(16) unsigned short exl[2048];       // bf16 Ext_X cols [b*256+t][4]
  __shared__ float t0l[512];                               // T0 f32
  __shared__ float hvitl[512];                             // HVAC + int_all f32
  __shared__ __align__(16) float parts[16];                // fc2 partials [b][wv] CONTIGUOUS

  const int tid = threadIdx.x;
  const int wv  = tid >> 6;             // 0..7
  const int ln  = tid & 63;
  const int l15 = ln & 15;
  const int quad= ln >> 4;
  const int bb  = blockIdx.x;

  // ---- init: stage per-block tables ----
  {
    int b=tid>>8, tt=tid&255;
    const float* row = in + (2*bb+b)*1792 + tt*7;
    t0l[tid] = row[0];
    exl[tid*4+0]=f2bf(row[1]); exl[tid*4+1]=f2bf(row[2]);
    exl[tid*4+2]=f2bf(row[3]); exl[tid*4+3]=f2bf(row[4]);
  }
  for(int p=tid; p<2*HLENb; p+=512) ((signed char*)hbuf)[p]=0;
  if(tid<16) toutl[(tid>>3)*256+(tid&7)] = f2bf(in[(2*bb+(tid>>3))*1792+(tid&7)*7]);
  float* lw4 = scratch;
  float* l3  = scratch + 512;
  if(tid<128){
    lw4[tid*4+0]=i1w[tid*3+0]; lw4[tid*4+1]=i1w[tid*3+1];
    lw4[tid*4+2]=i1w[tid*3+2]; lw4[tid*4+3]=i1b[tid];
    l3[tid]=i3w[tid];
  }
  __syncthreads();
  if(tid<256) hbuf[0][((tid>>7)? HB1b:HB0b) + (tid&127)] = 127;   // h=1.0 -> q=127

  // ---- fused int module (one (b,t) per thread) ----
  {
    const float b30=i3b[0], sc0=scw[0];
    int b=tid>>8, t=tid&255;
    const float* row = in + (2*bb+b)*1792 + t*7;
    float x0=row[3],x1=row[4],x2=row[5], acc=0.f;
    #pragma unroll 8
    for(int j=0;j<128;j++){
      float r=fmaxf(lw4[j*4]*x0+lw4[j*4+1]*x1+lw4[j*4+2]*x2+lw4[j*4+3],0.f);
      acc += r*l3[j];
    }
    float v = rcpf(1.f+__expf(-(acc+b30)))*sc0;
    float itv = (t<8)?0.f:v;
    int gb = 2*bb+b;
    hvitl[tid] = row[6] + itv;
    out[3*BT+gb*256+t]=itv;              // Int_list
    out[BT+gb*256+t]=row[6];             // HVAC_list
    if(t<8){ out[gb*256+t]=row[0]; out[2*BT+gb*256+t]=0.f; }
  }

  // ---- i8 weight quantization (per-row scale) into VGPRs ----
  int4v wq[4][2];        // [gate][K-chunk], rows n = 128g + 16wv + l15
  float dq[4];
  short8 xfr[4];         // W_ih bf16 (pre-scaled by log2e), K=32 pad (5 valid)
  float  bsum[4];
  float  wihc[4];        // Wih[n,0]*log2e -- slot-7 deferred-correction coeff
  #pragma unroll
  for(int g=0;g<4;g++){
    int n = 128*g + 16*wv + l15;
    bsum[g] = (bih[n]+bhh[n])*LOG2E;
    wihc[g] = Wih[n*5]*LOG2E;
    const float* wr = Whh + n*128;
    float mx = 1e-20f;
    for(int j=0;j<128;j++) mx = fmaxf(mx, fabsf(wr[j]));
    float qs = 127.f/mx;
    dq[g] = mx * (LOG2E/16129.f);        // log2e/127^2
    #pragma unroll
    for(int c=0;c<2;c++){
      int4v v4;
      #pragma unroll
      for(int d=0;d<4;d++){
        int pk=0;
        #pragma unroll
        for(int bq=0;bq<4;bq++){
          int kk = c*64 + quad*16 + d*4 + bq;
          int q = __float2int_rn(wr[kk]*qs);
          pk |= (q & 255) << (8*bq);
        }
        v4[d]=pk;
      }
      wq[g][c]=v4;
    }
    short8 f;
    #pragma unroll
    for(int j=0;j<8;j++){ int kk=quad*8+j; f[j]=(short)f2bf(kk<5?Wih[n*5+kk]*LOG2E:0.f); }
    xfr[g]=f;
  }
  int4v fq[2]; float dqf;                // fc1 i8 (NOT log2e-scaled), row n2 = 16wv + l15
  {
    int n2 = 16*wv + l15;
    const float* fr = fc1w + n2*128;
    float mx = 1e-20f;
    for(int j=0;j<128;j++) mx = fmaxf(mx, fabsf(fr[j]));
    float qs = 127.f/mx;
    dqf = mx * (1.f/16129.f);
    #pragma unroll
    for(int c=0;c<2;c++){
      int4v v4;
      #pragma unroll
      for(int d=0;d<4;d++){
        int pk=0;
        #pragma unroll
        for(int bq=0;bq<4;bq++){
          int kk = c*64 + quad*16 + d*4 + bq;
          int q = __float2int_rn(fr[kk]*qs);
          pk |= (q & 255) << (8*bq);
        }
        v4[d]=pk;
      }
      fq[c]=v4;
    }
  }

  // ---- per-lane persistent scalars ----
  const int  u     = 16*wv + l15;           // this lane's unit
  const int  bm    = quad & 1;              // this lane's batch (quads 2/3 dup)
  const int  arow  = ((l15&3)==0) ? (((l15>>2)&1)? HB1b : HB0b) : 0;  // 0 = zero region
  const int  aoff  = arow + quad*16;
  const int  hwoff = (bm? HB1b:HB0b) + u;
  const int  bpa0  = ((quad&1)<<7) | (l15<<2);  // bpermute byte addr, k<4
  const int  bpa1  = bpa0 + 64;                 // k>=4
  const float fb    = fc1b[u];
  const float fcw_u = fc2w[u];
  const float fc2b0 = fc2b[0];
  const float zwv   = zonew[0];
  const floatx4 ZV  = {0.f,0.f,0.f,0.f};
  const int4v   ZI  = {0,0,0,0};
  const short8  Z8  = 0;
  float E0 = in[(2*bb)*1792 + 56];          // E in EVERY lane's registers
  float E1 = in[(2*bb+1)*1792 + 56];
  float c0 = 1.f;
  __syncthreads();                          // staging visible

  float xv[8][4];                           // x-gates for CURRENT iter
  float xvn[8][4];                          // x-gates bulk for NEXT iter

  // bulk x-gate builder for target iteration `it`.
  // exact7: slot-7 uses the full tmix (E known) -- prologue only.
  // deferred (loop): slot-7 carries only t0*ratio; slot 6 (p=it-1) uses the
  // E registers (toutl[it-1] is written this same phase -> racy via LDS).
  auto bulk = [&](int it, bool exact7, float (&dst)[8][4]) {
    short8 ea = Z8;
    if(quad==0){
      int bE=l15>>3, kk=l15&7, p=it-7+kk;
      bool lt = (it<128);
      float ratio=(float)it*0.0078125f;
      float tmix;
      if(kk==7){
        if(exact7){
          float tos = bE? E1:E0;
          tmix = lt ? t0l[bE*256+it]*ratio + tos*(1.f-ratio) : tos;
        } else {
          tmix = lt ? t0l[bE*256+it]*ratio : 0.f;
        }
      } else if(kk==6){
        float tos = exact7 ? bf2f(toutl[bE*256+p]) : (bE? E1:E0);
        tmix = lt ? t0l[bE*256+p]*ratio + tos*(1.f-ratio) : tos;
      } else {
        float tos = bf2f(toutl[bE*256+p]);
        tmix = lt ? t0l[bE*256+p]*ratio + tos*(1.f-ratio) : tos;
      }
      ea[0]=(short)f2bf(tmix);
      ushort4v e4 = *(const ushort4v*)&exl[(bE*256+p)*4];
      ea[1]=(short)e4[0]; ea[2]=(short)e4[1];
      ea[3]=(short)e4[2]; ea[4]=(short)e4[3];
    }
    #pragma unroll
    for(int g=0;g<4;g++){
      floatx4 z=__builtin_amdgcn_mfma_f32_16x16x32_bf16(ea, xfr[g], ZV,0,0,0);
      #pragma unroll
      for(int r=0;r<4;r++){
        int zi = __float_as_int(z[r]+bsum[g]);
        dst[r][g]   = __int_as_float(__builtin_amdgcn_ds_bpermute(bpa0, zi));
        dst[r+4][g] = __int_as_float(__builtin_amdgcn_ds_bpermute(bpa1, zi));
      }
    }
  };

  bulk(8, true, xv);                        // prologue: xv(8) exact

  #pragma unroll 1
  for(int i=8;i<256;i++){
    // ===== phase A (on-chain): E-update, slot-7 correction, xvn->xv =====
    if(i>8){
      floatx4 pa=*(const floatx4*)&parts[0];
      floatx4 pb=*(const floatx4*)&parts[4];
      floatx4 pc=*(const floatx4*)&parts[8];
      floatx4 pd=*(const floatx4*)&parts[12];
      float ext0=((pa[0]+pa[1])+(pa[2]+pa[3]))+((pb[0]+pb[1])+(pb[2]+pb[3]))+fc2b0;
      float ext1=((pc[0]+pc[1])+(pc[2]+pc[3]))+((pd[0]+pd[1])+(pd[2]+pd[3]))+fc2b0;
      int ip = i-1;
      float tot0 = ext0 + hvitl[ip];
      float tot1 = ext1 + hvitl[256+ip];
      if(ip<128){
        float ratio=(float)ip*0.0078125f;
        E0 = ratio*t0l[ip]     + (1.f-ratio)*E0 + tot0*zwv;
        E1 = ratio*t0l[256+ip] + (1.f-ratio)*E1 + tot1*zwv;
      } else {
        E0 += tot0*zwv;
        E1 += tot1*zwv;
      }
      if(tid==0){ extl[ip]=f2bf(ext0); extl[256+ip]=f2bf(ext1); }
      // deferred slot-7 correction + register handoff xvn -> xv
      float kap = (i<128) ? (1.f-(float)i*0.0078125f) : 1.f;
      float ce  = kap * (bm ? E1 : E0);
      #pragma unroll
      for(int k2=0;k2<7;k2++)
        #pragma unroll
        for(int g=0;g<4;g++) xv[k2][g]=xvn[k2][g];
      #pragma unroll
      for(int g=0;g<4;g++) xv[7][g] = fmaf(ce, wihc[g], xvn[7][g]);
    }
    if(tid==0){ toutl[i]=f2bf(E0); toutl[256+i]=f2bf(E1); }   // TOut[:,i]=E

    // hoist k=0's h reads (hbuf[0] fenced by prev iter's fc barrier)
    int4v a0h = *(const int4v*)(&hbuf[0][0] + aoff);
    int4v a1h = *(const int4v*)(&hbuf[0][0] + aoff + 64);

    // bulk xvn for iter i+1 (off-chain; results consumed next phase A)
    if(i<255) bulk(i+1, false, xvn);

    // ===== 8 inner LSTM steps: 8 i8 MFMAs/wave, single nonlin chain =====
    #pragma unroll
    for(int k=0;k<8;k++){
      const signed char* hb = &hbuf[k&1][0];
      int4v a0, a1;
      if(k==0){ a0=a0h; a1=a1h; }
      else { a0 = *(const int4v*)(hb + aoff); a1 = *(const int4v*)(hb + aoff + 64); }
      int accs[4];
      #pragma unroll
      for(int g=0;g<4;g++){
        int4v za = __builtin_amdgcn_mfma_i32_16x16x64_i8(a0, wq[g][0], ZI,0,0,0);
        int4v zb = __builtin_amdgcn_mfma_i32_16x16x64_i8(a1, wq[g][1], ZI,0,0,0);
        accs[g] = za[0]+zb[0];
      }
      float gi=fmaf((float)accs[0],dq[0],xv[k][0]);   // all in log2e domain
      float gf=fmaf((float)accs[1],dq[1],xv[k][1]);
      float gg=fmaf((float)accs[2],dq[2],xv[k][2]);
      float go=fmaf((float)accs[3],dq[3],xv[k][3]);
      float ef =ex2(-gf);                             // bare v_exp
      float egi=ex2(-gi);
      float egg=ex2(-2.f*gg);
      float sf = rcpf(1.f+ef);
      float itn=(1.f-egg)*rcpf((1.f+egi)*(1.f+egg));
      c0 = sf*c0 + itn;
      float ego=ex2(-go);
      float ec =ex2(-2.8853900818f*c0);               // c unscaled: x2log2e
      float hv2=(1.f-ec)*rcpf((1.f+ego)*(1.f+ec));
      int q = __float2int_rn(hv2*127.f);              // |h|<1 -> |q|<=127
      hbuf[(k+1)&1][hwoff] = (signed char)q;          // quads 2/3 dup same value
      __syncthreads();
    }

    // ===== fc1 (i8) + within-quad fc2 reduce (both batches in parallel) =====
    {
      const signed char* hb = &hbuf[0][0];
      int4v a0 = *(const int4v*)(hb + aoff);
      int4v a1 = *(const int4v*)(hb + aoff + 64);
      int4v za = __builtin_amdgcn_mfma_i32_16x16x64_i8(a0, fq[0], ZI,0,0,0);
      int4v zb = __builtin_amdgcn_mfma_i32_16x16x64_i8(a1, fq[1], ZI,0,0,0);
      float fv = (float)(za[0]+zb[0])*dqf + fb;
      float pv = fmaxf(fv,0.f)*fcw_u;
      pv += __shfl_xor(pv, 1, 64);       // xor{1,2,4,8} stays within quad:
      pv += __shfl_xor(pv, 2, 64);       // quad0/2 reduce batch0, quad1/3 batch1
      pv += __shfl_xor(pv, 4, 64);
      pv += __shfl_xor(pv, 8, 64);
      if(ln==0)       parts[wv]   = pv;  // batch0 block: parts[0..7]
      else if(ln==16) parts[8+wv] = pv;  // batch1 block: parts[8..15]
    }
    __syncthreads();
  }

  // ===== tail: ext(255) from last fc =====
  if(tid==0){
    float ext0 = ((parts[0]+parts[1])+(parts[2]+parts[3]))
               + ((parts[4]+parts[5])+(parts[6]+parts[7])) + fc2b0;
    float ext1 = ((parts[8]+parts[9])+(parts[10]+parts[11]))
               + ((parts[12]+parts[13])+(parts[14]+parts[15])) + fc2b0;
    extl[255]=f2bf(ext0); extl[511]=f2bf(ext1);
  }
  __syncthreads();

  // ===== flush TOut / Ext_list from LDS =====
  for(int p=tid; p<496; p+=512){
    int b = (p>=248) ? 1 : 0;
    int i2 = p - b*248 + 8;
    int gb = 2*bb + b;
    out[gb*256+i2]      = bf2f(toutl[b*256+i2]);
    out[2*BT+gb*256+i2] = bf2f(extl[b*256+i2]);
  }
}

extern "C" void kernel_launch(void* const* d_in, const int* in_sizes, int n_in,
                              void* d_out, int out_size, void* d_ws, size_t ws_size,
                              hipStream_t stream)
{
  const float* in   = (const float*)d_in[0];
  const float* Wih  = (const float*)d_in[1];
  const float* Whh  = (const float*)d_in[2];
  const float* bih  = (const float*)d_in[3];
  const float* bhh  = (const float*)d_in[4];
  const float* fc1w = (const float*)d_in[5];
  const float* fc1b = (const float*)d_in[6];
  const float* fc2w = (const float*)d_in[7];
  const float* fc2b = (const float*)d_in[8];
  const float* i1w  = (const float*)d_in[9];
  const float* i1b  = (const float*)d_in[10];
  const float* i3w  = (const float*)d_in[11];
  const float* i3b  = (const float*)d_in[12];
  const float* scw  = (const float*)d_in[13];
  const float* zw   = (const float*)d_in[14];
  float* out = (float*)d_out;

  k_seq<<<dim3(256), dim3(512), 0, stream>>>(in, Wih, Whh, bih, bhh,
                                             fc1w, fc1b, fc2w, fc2b,
                                             i1w, i1b, i3w, i3b, scw, zw, out);
}

// Round 7
// 1048.342 us; speedup vs baseline: 1.3872x; 1.0579x over previous
//
#include <hip/hip_runtime.h>

#define BT   (512*256)
// hbuf (bytes): zeros @0..127, pad, b0 h @192..319, b1 h @336..463.
// HB0b==64 (mod 128): h lines banks 16-31 for a0 / 0-15 for a1, opposite the
// zero-lane broadcast banks. HB1b=336 (==80 mod 128): batch1 lines shifted 4
// banks vs batch0 -> reads stay <=2-way (free), and the per-step h WRITES of
// quad0 (b0) and quad1 (b1) land on 8 disjoint dword-banks.
#define HB0b 192
#define HB1b 336
#define HLENb 464
#define LOG2E 1.44269504088896f

using short8  = __attribute__((ext_vector_type(8))) short;
using floatx4 = __attribute__((ext_vector_type(4))) float;
using int4v   = __attribute__((ext_vector_type(4))) int;
using ushort4v= __attribute__((ext_vector_type(4))) unsigned short;

__device__ inline unsigned short f2bf(float f){
  unsigned int u = __float_as_uint(f);
  u += 0x7FFFu + ((u >> 16) & 1u);          // RNE
  return (unsigned short)(u >> 16);
}
__device__ inline float bf2f(unsigned short u){
  return __uint_as_float(((unsigned int)u) << 16);
}
__device__ inline float rcpf(float x){ return __builtin_amdgcn_rcpf(x); }
__device__ inline float ex2(float x){ return __builtin_amdgcn_exp2f(x); }

// 256 blocks x 512 threads = round-1 (969us) structure. Round-6's cross-iter
// phase-A pipelining REVERTED (DS ops retire in order -> bpermute queue lands
// on every inner lgkmcnt wait; +20 VGPR; measured -14%). This round keeps the
// proven chain and removes measured fat:
//  (1) h-write predicated to ln<32 -- quads 2/3 wrote duplicate bytes; 64
//      lanes on 8 dwords (~8-way serialize) -> 32 lanes on 8 dwords (4-way).
//  (2) HB1b 320->336: batch0/batch1 write dwords now on disjoint banks
//      (were identical banks: offset 128 == 0 mod 128).
//  (3) inner K-chunk MFMAs independent + scalar add (round-4-verified):
//      removes the chained-MFMA dependency from each step's serial path.
//  (4) phase-A x-gates packed bf16 via v_cvt_pk_bf16_f32 before bpermute
//      (round-4-verified numerics): 16 bpermutes instead of 32, -16 VGPR.
__global__ __launch_bounds__(512,1) void k_seq(
    const float* __restrict__ in,
    const float* __restrict__ Wih,  const float* __restrict__ Whh,
    const float* __restrict__ bih,  const float* __restrict__ bhh,
    const float* __restrict__ fc1w, const float* __restrict__ fc1b,
    const float* __restrict__ fc2w, const float* __restrict__ fc2b,
    const float* __restrict__ i1w,  const float* __restrict__ i1b,
    const float* __restrict__ i3w,  const float* __restrict__ i3b,
    const float* __restrict__ scw,  const float* __restrict__ zonew,
    float* __restrict__ out)
{
  __shared__ __align__(16) signed char hbuf[2][HLENb];     // i8 h + zero region
  __shared__ __align__(16) float scratch[640];             // int-module weights
  __shared__ __align__(8)  unsigned short toutl[512];      // bf16 TOut history [b][256]
  __shared__ __align__(8)  unsigned short extl[512];       // bf16 Ext results [b][256]
  __shared__ __align__(16) unsigned short exl[2048];       // bf16 Ext_X cols [b*256+t][4]
  __shared__ float t0l[512];                               // T0 f32
  __shared__ float hvitl[512];                             // HVAC + int_all f32
  __shared__ __align__(16) float parts[16];                // fc2 partials [b][wv] contiguous

  const int tid = threadIdx.x;
  const int wv  = tid >> 6;             // 0..7
  const int ln  = tid & 63;
  const int l15 = ln & 15;
  const int quad= ln >> 4;
  const int bb  = blockIdx.x;

  // ---- init: stage per-block tables ----
  {
    int b=tid>>8, tt=tid&255;
    const float* row = in + (2*bb+b)*1792 + tt*7;
    t0l[tid] = row[0];
    exl[tid*4+0]=f2bf(row[1]); exl[tid*4+1]=f2bf(row[2]);
    exl[tid*4+2]=f2bf(row[3]); exl[tid*4+3]=f2bf(row[4]);
  }
  for(int p=tid; p<2*HLENb; p+=512) ((signed char*)hbuf)[p]=0;
  if(tid<16) toutl[(tid>>3)*256+(tid&7)] = f2bf(in[(2*bb+(tid>>3))*1792+(tid&7)*7]);
  float* lw4 = scratch;
  float* l3  = scratch + 512;
  if(tid<128){
    lw4[tid*4+0]=i1w[tid*3+0]; lw4[tid*4+1]=i1w[tid*3+1];
    lw4[tid*4+2]=i1w[tid*3+2]; lw4[tid*4+3]=i1b[tid];
    l3[tid]=i3w[tid];
  }
  __syncthreads();
  if(tid<256) hbuf[0][((tid>>7)? HB1b:HB0b) + (tid&127)] = 127;   // h=1.0 -> q=127

  // ---- fused int module (one (b,t) per thread) ----
  {
    const float b30=i3b[0], sc0=scw[0];
    int b=tid>>8, t=tid&255;
    const float* row = in + (2*bb+b)*1792 + t*7;
    float x0=row[3],x1=row[4],x2=row[5], acc=0.f;
    #pragma unroll 8
    for(int j=0;j<128;j++){
      float r=fmaxf(lw4[j*4]*x0+lw4[j*4+1]*x1+lw4[j*4+2]*x2+lw4[j*4+3],0.f);
      acc += r*l3[j];
    }
    float v = rcpf(1.f+__expf(-(acc+b30)))*sc0;
    float itv = (t<8)?0.f:v;
    int gb = 2*bb+b;
    hvitl[tid] = row[6] + itv;
    out[3*BT+gb*256+t]=itv;              // Int_list
    out[BT+gb*256+t]=row[6];             // HVAC_list
    if(t<8){ out[gb*256+t]=row[0]; out[2*BT+gb*256+t]=0.f; }
  }

  // ---- i8 weight quantization (per-row scale) into VGPRs ----
  int4v wq[4][2];        // [gate][K-chunk], rows n = 128g + 16wv + l15
  float dq[4];
  short8 xfr[4];         // W_ih bf16 (pre-scaled by log2e), K=32 pad (5 valid)
  float  bsum[4];
  #pragma unroll
  for(int g=0;g<4;g++){
    int n = 128*g + 16*wv + l15;
    bsum[g] = (bih[n]+bhh[n])*LOG2E;
    const float* wr = Whh + n*128;
    float mx = 1e-20f;
    for(int j=0;j<128;j++) mx = fmaxf(mx, fabsf(wr[j]));
    float qs = 127.f/mx;
    dq[g] = mx * (LOG2E/16129.f);        // log2e/127^2
    #pragma unroll
    for(int c=0;c<2;c++){
      int4v v4;
      #pragma unroll
      for(int d=0;d<4;d++){
        int pk=0;
        #pragma unroll
        for(int bq=0;bq<4;bq++){
          int kk = c*64 + quad*16 + d*4 + bq;
          int q = __float2int_rn(wr[kk]*qs);
          pk |= (q & 255) << (8*bq);
        }
        v4[d]=pk;
      }
      wq[g][c]=v4;
    }
    short8 f;
    #pragma unroll
    for(int j=0;j<8;j++){ int kk=quad*8+j; f[j]=(short)f2bf(kk<5?Wih[n*5+kk]*LOG2E:0.f); }
    xfr[g]=f;
  }
  int4v fq[2]; float dqf;                // fc1 i8 (NOT log2e-scaled), row n2 = 16wv + l15
  {
    int n2 = 16*wv + l15;
    const float* fr = fc1w + n2*128;
    float mx = 1e-20f;
    for(int j=0;j<128;j++) mx = fmaxf(mx, fabsf(fr[j]));
    float qs = 127.f/mx;
    dqf = mx * (1.f/16129.f);
    #pragma unroll
    for(int c=0;c<2;c++){
      int4v v4;
      #pragma unroll
      for(int d=0;d<4;d++){
        int pk=0;
        #pragma unroll
        for(int bq=0;bq<4;bq++){
          int kk = c*64 + quad*16 + d*4 + bq;
          int q = __float2int_rn(fr[kk]*qs);
          pk |= (q & 255) << (8*bq);
        }
        v4[d]=pk;
      }
      fq[c]=v4;
    }
  }

  // ---- per-lane persistent scalars ----
  const int  u     = 16*wv + l15;           // this lane's unit
  const int  bm    = quad & 1;              // this lane's batch (quads 2/3 dup)
  const int  arow  = ((l15&3)==0) ? (((l15>>2)&1)? HB1b : HB0b) : 0;  // 0 = zero region
  const int  aoff  = arow + quad*16;
  const int  hwoff = (bm? HB1b:HB0b) + u;
  const int  bpa0  = ((quad&1)<<7) | (l15<<2);  // bpermute byte addr, k<4
  const int  bpa1  = bpa0 + 64;                 // k>=4
  const float fb    = fc1b[u];
  const float fcw_u = fc2w[u];
  const float fc2b0 = fc2b[0];
  const float zwv   = zonew[0];
  const floatx4 ZV  = {0.f,0.f,0.f,0.f};
  const int4v   ZI  = {0,0,0,0};
  const short8  Z8  = 0;
  float E0 = in[(2*bb)*1792 + 56];          // E in EVERY lane's registers
  float E1 = in[(2*bb+1)*1792 + 56];
  float c0 = 1.f;
  __syncthreads();                          // int scratch retired

  #pragma unroll 1
  for(int i=8;i<256;i++){
    // ===== phase A: deferred E-update (i-1), TOut, embed, x-MFMA+pack+bpermute =====
    if(i>8){
      floatx4 pa=*(const floatx4*)&parts[0];
      floatx4 pb=*(const floatx4*)&parts[4];
      floatx4 pc=*(const floatx4*)&parts[8];
      floatx4 pd=*(const floatx4*)&parts[12];
      float ext0=((pa[0]+pa[1])+(pa[2]+pa[3]))+((pb[0]+pb[1])+(pb[2]+pb[3]))+fc2b0;
      float ext1=((pc[0]+pc[1])+(pc[2]+pc[3]))+((pd[0]+pd[1])+(pd[2]+pd[3]))+fc2b0;
      int ip = i-1;
      float tot0 = ext0 + hvitl[ip];
      float tot1 = ext1 + hvitl[256+ip];
      if(ip<128){
        float ratio=(float)ip*0.0078125f;
        E0 = ratio*t0l[ip]     + (1.f-ratio)*E0 + tot0*zwv;
        E1 = ratio*t0l[256+ip] + (1.f-ratio)*E1 + tot1*zwv;
      } else {
        E0 += tot0*zwv;
        E1 += tot1*zwv;
      }
      if(tid==0){ extl[ip]=f2bf(ext0); extl[256+ip]=f2bf(ext1); }
    }
    if(tid==0){ toutl[i]=f2bf(E0); toutl[256+i]=f2bf(E1); }   // TOut[:,i]=E
    int xvp[8][2];                        // packed bf16 x-gate pairs [k][{i|f, g|o}]
    {
      short8 ea = Z8;
      if(quad==0){
        int bE=l15>>3, kk=l15&7, p=i-7+kk;
        float tos = (p==i) ? (bE? E1:E0) : bf2f(toutl[bE*256+p]);
        float tmix;
        if(i<128){
          float ratio=(float)i*0.0078125f;
          tmix = t0l[bE*256+p]*ratio + tos*(1.f-ratio);
        } else tmix = tos;
        ea[0]=(short)f2bf(tmix);
        ushort4v e4 = *(const ushort4v*)&exl[(bE*256+p)*4];
        ea[1]=(short)e4[0]; ea[2]=(short)e4[1];
        ea[3]=(short)e4[2]; ea[4]=(short)e4[3];
      }
      #pragma unroll
      for(int gp=0; gp<2; gp++){             // gate pairs (i,f) and (g,o)
        floatx4 zl=__builtin_amdgcn_mfma_f32_16x16x32_bf16(ea, xfr[2*gp],   ZV,0,0,0);
        floatx4 zh=__builtin_amdgcn_mfma_f32_16x16x32_bf16(ea, xfr[2*gp+1], ZV,0,0,0);
        #pragma unroll
        for(int r=0;r<4;r++){
          float lo = zl[r]+bsum[2*gp];
          float hi = zh[r]+bsum[2*gp+1];
          int pk;
          asm("v_cvt_pk_bf16_f32 %0, %1, %2" : "=v"(pk) : "v"(lo), "v"(hi));
          xvp[r][gp]   = __builtin_amdgcn_ds_bpermute(bpa0, pk);  // row r   (k=r)
          xvp[r+4][gp] = __builtin_amdgcn_ds_bpermute(bpa1, pk);  // row r+4 (k=r+4)
        }
      }
    }
    // NO barrier here: hbuf/parts already fenced by prev iter's barriers.

    // ===== 8 inner LSTM steps: 8 i8 MFMAs/wave, single nonlin chain =====
    #pragma unroll
    for(int k=0;k<8;k++){
      const signed char* hb = &hbuf[k&1][0];
      int4v a0 = *(const int4v*)(hb + aoff);        // K 0..63
      int4v a1 = *(const int4v*)(hb + aoff + 64);   // K 64..127
      int accs[4];
      #pragma unroll
      for(int g=0;g<4;g++){
        int4v za = __builtin_amdgcn_mfma_i32_16x16x64_i8(a0, wq[g][0], ZI,0,0,0);
        int4v zb = __builtin_amdgcn_mfma_i32_16x16x64_i8(a1, wq[g][1], ZI,0,0,0);
        accs[g] = za[0]+zb[0];                      // independent MFMAs, 1 add
      }
      int p0=xvp[k][0], p1=xvp[k][1];
      float xi = __uint_as_float(((unsigned)p0)<<16);
      float xf = __uint_as_float((unsigned)p0 & 0xffff0000u);
      float xgg= __uint_as_float(((unsigned)p1)<<16);
      float xo = __uint_as_float((unsigned)p1 & 0xffff0000u);
      float gi=fmaf((float)accs[0],dq[0],xi);       // all in log2e domain
      float gf=fmaf((float)accs[1],dq[1],xf);
      float gg=fmaf((float)accs[2],dq[2],xgg);
      float go=fmaf((float)accs[3],dq[3],xo);
      float ef =ex2(-gf);                           // bare v_exp
      float egi=ex2(-gi);
      float egg=ex2(-2.f*gg);
      float sf = rcpf(1.f+ef);
      float itn=(1.f-egg)*rcpf((1.f+egi)*(1.f+egg));
      c0 = sf*c0 + itn;
      float ego=ex2(-go);
      float ec =ex2(-2.8853900818f*c0);             // c unscaled: x2log2e
      float hv2=(1.f-ec)*rcpf((1.f+ego)*(1.f+ec));
      int q = __float2int_rn(hv2*127.f);            // |h|<1 -> |q|<=127
      if(ln<32) hbuf[(k+1)&1][hwoff] = (signed char)q;  // quads 2/3 were dup writers
      __syncthreads();
    }

    // ===== fc1 (i8) + within-quad fc2 reduce (both batches in parallel) =====
    {
      const signed char* hb = &hbuf[0][0];
      int4v a0 = *(const int4v*)(hb + aoff);
      int4v a1 = *(const int4v*)(hb + aoff + 64);
      int4v za = __builtin_amdgcn_mfma_i32_16x16x64_i8(a0, fq[0], ZI,0,0,0);
      int4v zb = __builtin_amdgcn_mfma_i32_16x16x64_i8(a1, fq[1], ZI,0,0,0);
      float fv = (float)(za[0]+zb[0])*dqf + fb;
      float pv = fmaxf(fv,0.f)*fcw_u;
      pv += __shfl_xor(pv, 1, 64);       // xor{1,2,4,8} stays within quad:
      pv += __shfl_xor(pv, 2, 64);       // quad0/2 reduce batch0, quad1/3 batch1
      pv += __shfl_xor(pv, 4, 64);
      pv += __shfl_xor(pv, 8, 64);
      if(ln==0)       parts[wv]   = pv;  // batch0 block: parts[0..7]
      else if(ln==16) parts[8+wv] = pv;  // batch1 block: parts[8..15]
    }
    __syncthreads();
  }

  // ===== tail: ext(255) from last fc =====
  if(tid==0){
    float ext0 = ((parts[0]+parts[1])+(parts[2]+parts[3]))
               + ((parts[4]+parts[5])+(parts[6]+parts[7])) + fc2b0;
    float ext1 = ((parts[8]+parts[9])+(parts[10]+parts[11]))
               + ((parts[12]+parts[13])+(parts[14]+parts[15])) + fc2b0;
    extl[255]=f2bf(ext0); extl[511]=f2bf(ext1);
  }
  __syncthreads();

  // ===== flush TOut / Ext_list from LDS =====
  for(int p=tid; p<496; p+=512){
    int b = (p>=248) ? 1 : 0;
    int i2 = p - b*248 + 8;
    int gb = 2*bb + b;
    out[gb*256+i2]      = bf2f(toutl[b*256+i2]);
    out[2*BT+gb*256+i2] = bf2f(extl[b*256+i2]);
  }
}

extern "C" void kernel_launch(void* const* d_in, const int* in_sizes, int n_in,
                              void* d_out, int out_size, void* d_ws, size_t ws_size,
                              hipStream_t stream)
{
  const float* in   = (const float*)d_in[0];
  const float* Wih  = (const float*)d_in[1];
  const float* Whh  = (const float*)d_in[2];
  const float* bih  = (const float*)d_in[3];
  const float* bhh  = (const float*)d_in[4];
  const float* fc1w = (const float*)d_in[5];
  const float* fc1b = (const float*)d_in[6];
  const float* fc2w = (const float*)d_in[7];
  const float* fc2b = (const float*)d_in[8];
  const float* i1w  = (const float*)d_in[9];
  const float* i1b  = (const float*)d_in[10];
  const float* i3w  = (const float*)d_in[11];
  const float* i3b  = (const float*)d_in[12];
  const float* scw  = (const float*)d_in[13];
  const float* zw   = (const float*)d_in[14];
  float* out = (float*)d_out;

  k_seq<<<dim3(256), dim3(512), 0, stream>>>(in, Wih, Whh, bih, bhh,
                                             fc1w, fc1b, fc2w, fc2b,
                                             i1w, i1b, i3w, i3b, scw, zw, out);
}

// Round 8
// 1045.269 us; speedup vs baseline: 1.3913x; 1.0029x over previous
//
#include <hip/hip_runtime.h>

#define BT   (512*256)
// hbuf (bytes): zeros @0..127, pad, b0 h @192..319, b1 h @336..463.
// HB0b==64 (mod 128): h lines banks 16-31 for a0 / 0-15 for a1, opposite the
// zero-lane broadcast banks. HB1b=336 (==80 mod 128): batch1 shifted 4 banks
// vs batch0 -> reads stay <=2-way (free); per-step h WRITES of quad0 (b0) and
// quad1 (b1) hit 8 disjoint dword-banks.
#define HB0b 192
#define HB1b 336
#define HLENb 464
#define LOG2E 1.44269504088896f

using short8  = __attribute__((ext_vector_type(8))) short;
using floatx4 = __attribute__((ext_vector_type(4))) float;
using int4v   = __attribute__((ext_vector_type(4))) int;
using ushort4v= __attribute__((ext_vector_type(4))) unsigned short;

__device__ inline unsigned short f2bf(float f){
  unsigned int u = __float_as_uint(f);
  u += 0x7FFFu + ((u >> 16) & 1u);          // RNE
  return (unsigned short)(u >> 16);
}
__device__ inline float bf2f(unsigned short u){
  return __uint_as_float(((unsigned int)u) << 16);
}
__device__ inline float rcpf(float x){ return __builtin_amdgcn_rcpf(x); }
__device__ inline float ex2(float x){ return __builtin_amdgcn_exp2f(x); }

// 256 blocks x 512 threads = round-1 (969us) structure VERBATIM except:
//  (1) HB1b 320->336: batch0/batch1 h-write dwords on disjoint banks.
//  (2) h-write predicated to ln<32 (quads 2/3 were duplicate writers).
// Round-7 post-mortem: these two cut SQ_LDS_BANK_CONFLICT 4.19e7->1.75e7
// (verified), but the bundled inner-loop edits (independent MFMA+add, packed
// bf16 x-gates) regressed the chain -- both REVERTED to round-1's chained
// MFMAs + f32 xv. One attributable delta per round.
__global__ __launch_bounds__(512,1) void k_seq(
    const float* __restrict__ in,
    const float* __restrict__ Wih,  const float* __restrict__ Whh,
    const float* __restrict__ bih,  const float* __restrict__ bhh,
    const float* __restrict__ fc1w, const float* __restrict__ fc1b,
    const float* __restrict__ fc2w, const float* __restrict__ fc2b,
    const float* __restrict__ i1w,  const float* __restrict__ i1b,
    const float* __restrict__ i3w,  const float* __restrict__ i3b,
    const float* __restrict__ scw,  const float* __restrict__ zonew,
    float* __restrict__ out)
{
  __shared__ __align__(16) signed char hbuf[2][HLENb];     // i8 h + zero region
  __shared__ __align__(16) float scratch[640];             // int-module weights
  __shared__ __align__(8)  unsigned short toutl[512];      // bf16 TOut history [b][256]
  __shared__ __align__(8)  unsigned short extl[512];       // bf16 Ext results [b][256]
  __shared__ __align__(16) unsigned short exl[2048];       // bf16 Ext_X cols [b*256+t][4]
  __shared__ float t0l[512];                               // T0 f32
  __shared__ float hvitl[512];                             // HVAC + int_all f32
  __shared__ __align__(16) float parts[16];                // fc2 partials [b][wv] contiguous

  const int tid = threadIdx.x;
  const int wv  = tid >> 6;             // 0..7
  const int ln  = tid & 63;
  const int l15 = ln & 15;
  const int quad= ln >> 4;
  const int bb  = blockIdx.x;

  // ---- init: stage per-block tables ----
  {
    int b=tid>>8, tt=tid&255;
    const float* row = in + (2*bb+b)*1792 + tt*7;
    t0l[tid] = row[0];
    exl[tid*4+0]=f2bf(row[1]); exl[tid*4+1]=f2bf(row[2]);
    exl[tid*4+2]=f2bf(row[3]); exl[tid*4+3]=f2bf(row[4]);
  }
  for(int p=tid; p<2*HLENb; p+=512) ((signed char*)hbuf)[p]=0;
  if(tid<16) toutl[(tid>>3)*256+(tid&7)] = f2bf(in[(2*bb+(tid>>3))*1792+(tid&7)*7]);
  float* lw4 = scratch;
  float* l3  = scratch + 512;
  if(tid<128){
    lw4[tid*4+0]=i1w[tid*3+0]; lw4[tid*4+1]=i1w[tid*3+1];
    lw4[tid*4+2]=i1w[tid*3+2]; lw4[tid*4+3]=i1b[tid];
    l3[tid]=i3w[tid];
  }
  __syncthreads();
  if(tid<256) hbuf[0][((tid>>7)? HB1b:HB0b) + (tid&127)] = 127;   // h=1.0 -> q=127

  // ---- fused int module (one (b,t) per thread) ----
  {
    const float b30=i3b[0], sc0=scw[0];
    int b=tid>>8, t=tid&255;
    const float* row = in + (2*bb+b)*1792 + t*7;
    float x0=row[3],x1=row[4],x2=row[5], acc=0.f;
    #pragma unroll 8
    for(int j=0;j<128;j++){
      float r=fmaxf(lw4[j*4]*x0+lw4[j*4+1]*x1+lw4[j*4+2]*x2+lw4[j*4+3],0.f);
      acc += r*l3[j];
    }
    float v = rcpf(1.f+__expf(-(acc+b30)))*sc0;
    float itv = (t<8)?0.f:v;
    int gb = 2*bb+b;
    hvitl[tid] = row[6] + itv;
    out[3*BT+gb*256+t]=itv;              // Int_list
    out[BT+gb*256+t]=row[6];             // HVAC_list
    if(t<8){ out[gb*256+t]=row[0]; out[2*BT+gb*256+t]=0.f; }
  }

  // ---- i8 weight quantization (per-row scale) into VGPRs ----
  int4v wq[4][2];        // [gate][K-chunk], rows n = 128g + 16wv + l15
  float dq[4];
  short8 xfr[4];         // W_ih bf16 (pre-scaled by log2e), K=32 pad (5 valid)
  float  bsum[4];
  #pragma unroll
  for(int g=0;g<4;g++){
    int n = 128*g + 16*wv + l15;
    bsum[g] = (bih[n]+bhh[n])*LOG2E;
    const float* wr = Whh + n*128;
    float mx = 1e-20f;
    for(int j=0;j<128;j++) mx = fmaxf(mx, fabsf(wr[j]));
    float qs = 127.f/mx;
    dq[g] = mx * (LOG2E/16129.f);        // log2e/127^2
    #pragma unroll
    for(int c=0;c<2;c++){
      int4v v4;
      #pragma unroll
      for(int d=0;d<4;d++){
        int pk=0;
        #pragma unroll
        for(int bq=0;bq<4;bq++){
          int kk = c*64 + quad*16 + d*4 + bq;
          int q = __float2int_rn(wr[kk]*qs);
          pk |= (q & 255) << (8*bq);
        }
        v4[d]=pk;
      }
      wq[g][c]=v4;
    }
    short8 f;
    #pragma unroll
    for(int j=0;j<8;j++){ int kk=quad*8+j; f[j]=(short)f2bf(kk<5?Wih[n*5+kk]*LOG2E:0.f); }
    xfr[g]=f;
  }
  int4v fq[2]; float dqf;                // fc1 i8 (NOT log2e-scaled), row n2 = 16wv + l15
  {
    int n2 = 16*wv + l15;
    const float* fr = fc1w + n2*128;
    float mx = 1e-20f;
    for(int j=0;j<128;j++) mx = fmaxf(mx, fabsf(fr[j]));
    float qs = 127.f/mx;
    dqf = mx * (1.f/16129.f);
    #pragma unroll
    for(int c=0;c<2;c++){
      int4v v4;
      #pragma unroll
      for(int d=0;d<4;d++){
        int pk=0;
        #pragma unroll
        for(int bq=0;bq<4;bq++){
          int kk = c*64 + quad*16 + d*4 + bq;
          int q = __float2int_rn(fr[kk]*qs);
          pk |= (q & 255) << (8*bq);
        }
        v4[d]=pk;
      }
      fq[c]=v4;
    }
  }

  // ---- per-lane persistent scalars ----
  const int  u     = 16*wv + l15;           // this lane's unit
  const int  bm    = quad & 1;              // this lane's batch (quads 2/3 dup)
  const int  arow  = ((l15&3)==0) ? (((l15>>2)&1)? HB1b : HB0b) : 0;  // 0 = zero region
  const int  aoff  = arow + quad*16;
  const int  hwoff = (bm? HB1b:HB0b) + u;
  const int  bpa0  = ((quad&1)<<7) | (l15<<2);  // bpermute byte addr, k<4
  const int  bpa1  = bpa0 + 64;                 // k>=4
  const float fb    = fc1b[u];
  const float fcw_u = fc2w[u];
  const float fc2b0 = fc2b[0];
  const float zwv   = zonew[0];
  const floatx4 ZV  = {0.f,0.f,0.f,0.f};
  const int4v   ZI  = {0,0,0,0};
  const short8  Z8  = 0;
  float E0 = in[(2*bb)*1792 + 56];          // E in EVERY lane's registers
  float E1 = in[(2*bb+1)*1792 + 56];
  float c0 = 1.f;
  __syncthreads();                          // int scratch retired

  #pragma unroll 1
  for(int i=8;i<256;i++){
    // ===== phase A: deferred E-update (i-1), TOut, embed, x-MFMA+bpermute =====
    if(i>8){
      floatx4 pa=*(const floatx4*)&parts[0];
      floatx4 pb=*(const floatx4*)&parts[4];
      floatx4 pc=*(const floatx4*)&parts[8];
      floatx4 pd=*(const floatx4*)&parts[12];
      float ext0=((pa[0]+pa[1])+(pa[2]+pa[3]))+((pb[0]+pb[1])+(pb[2]+pb[3]))+fc2b0;
      float ext1=((pc[0]+pc[1])+(pc[2]+pc[3]))+((pd[0]+pd[1])+(pd[2]+pd[3]))+fc2b0;
      int ip = i-1;
      float tot0 = ext0 + hvitl[ip];
      float tot1 = ext1 + hvitl[256+ip];
      if(ip<128){
        float ratio=(float)ip*0.0078125f;
        E0 = ratio*t0l[ip]     + (1.f-ratio)*E0 + tot0*zwv;
        E1 = ratio*t0l[256+ip] + (1.f-ratio)*E1 + tot1*zwv;
      } else {
        E0 += tot0*zwv;
        E1 += tot1*zwv;
      }
      if(tid==0){ extl[ip]=f2bf(ext0); extl[256+ip]=f2bf(ext1); }
    }
    if(tid==0){ toutl[i]=f2bf(E0); toutl[256+i]=f2bf(E1); }   // TOut[:,i]=E
    float xv[8][4];                        // x-gates, f32, register-resident
    {
      short8 ea = Z8;
      if(quad==0){
        int bE=l15>>3, kk=l15&7, p=i-7+kk;
        float tos = (p==i) ? (bE? E1:E0) : bf2f(toutl[bE*256+p]);
        float tmix;
        if(i<128){
          float ratio=(float)i*0.0078125f;
          tmix = t0l[bE*256+p]*ratio + tos*(1.f-ratio);
        } else tmix = tos;
        ea[0]=(short)f2bf(tmix);
        ushort4v e4 = *(const ushort4v*)&exl[(bE*256+p)*4];
        ea[1]=(short)e4[0]; ea[2]=(short)e4[1];
        ea[3]=(short)e4[2]; ea[4]=(short)e4[3];
      }
      #pragma unroll
      for(int g=0;g<4;g++){
        floatx4 z=__builtin_amdgcn_mfma_f32_16x16x32_bf16(ea, xfr[g], ZV,0,0,0);
        #pragma unroll
        for(int r=0;r<4;r++){
          int zi = __float_as_int(z[r]+bsum[g]);
          xv[r][g]   = __int_as_float(__builtin_amdgcn_ds_bpermute(bpa0, zi));
          xv[r+4][g] = __int_as_float(__builtin_amdgcn_ds_bpermute(bpa1, zi));
        }
      }
    }
    // NO barrier here: hbuf/parts already fenced by prev iter's barriers.

    // ===== 8 inner LSTM steps: 8 i8 MFMAs/wave, single nonlin chain =====
    #pragma unroll
    for(int k=0;k<8;k++){
      float xv0=xv[k][0], xv1=xv[k][1], xv2=xv[k][2], xv3=xv[k][3];
      const signed char* hb = &hbuf[k&1][0];
      int4v a0 = *(const int4v*)(hb + aoff);        // K 0..63
      int4v a1 = *(const int4v*)(hb + aoff + 64);   // K 64..127
      int4v acc[4];
      #pragma unroll
      for(int g=0;g<4;g++){
        int4v z = __builtin_amdgcn_mfma_i32_16x16x64_i8(a0, wq[g][0], ZI,0,0,0);
        z = __builtin_amdgcn_mfma_i32_16x16x64_i8(a1, wq[g][1], z,0,0,0);
        acc[g]=z;
      }
      float gi=fmaf((float)acc[0][0],dq[0],xv0);    // all in log2e domain
      float gf=fmaf((float)acc[1][0],dq[1],xv1);
      float gg=fmaf((float)acc[2][0],dq[2],xv2);
      float go=fmaf((float)acc[3][0],dq[3],xv3);
      float ef =ex2(-gf);                           // bare v_exp
      float egi=ex2(-gi);
      float egg=ex2(-2.f*gg);
      float sf = rcpf(1.f+ef);
      float itn=(1.f-egg)*rcpf((1.f+egi)*(1.f+egg));
      c0 = sf*c0 + itn;
      float ego=ex2(-go);
      float ec =ex2(-2.8853900818f*c0);             // c unscaled: x2log2e
      float hv2=(1.f-ec)*rcpf((1.f+ego)*(1.f+ec));
      int q = __float2int_rn(hv2*127.f);            // |h|<1 -> |q|<=127
      if(ln<32) hbuf[(k+1)&1][hwoff] = (signed char)q;  // quads 2/3 were dup writers
      __syncthreads();
    }

    // ===== fc1 (i8) + within-quad fc2 reduce (both batches in parallel) =====
    {
      const signed char* hb = &hbuf[0][0];
      int4v a0 = *(const int4v*)(hb + aoff);
      int4v a1 = *(const int4v*)(hb + aoff + 64);
      int4v z = __builtin_amdgcn_mfma_i32_16x16x64_i8(a0, fq[0], ZI,0,0,0);
      z = __builtin_amdgcn_mfma_i32_16x16x64_i8(a1, fq[1], z,0,0,0);
      float fv = (float)z[0]*dqf + fb;
      float pv = fmaxf(fv,0.f)*fcw_u;
      pv += __shfl_xor(pv, 1, 64);       // xor{1,2,4,8} stays within quad:
      pv += __shfl_xor(pv, 2, 64);       // quad0/2 reduce batch0, quad1/3 batch1
      pv += __shfl_xor(pv, 4, 64);
      pv += __shfl_xor(pv, 8, 64);
      if(ln==0)       parts[wv]   = pv;  // batch0 block: parts[0..7]
      else if(ln==16) parts[8+wv] = pv;  // batch1 block: parts[8..15]
    }
    __syncthreads();
  }

  // ===== tail: ext(255) from last fc =====
  if(tid==0){
    float ext0 = ((parts[0]+parts[1])+(parts[2]+parts[3]))
               + ((parts[4]+parts[5])+(parts[6]+parts[7])) + fc2b0;
    float ext1 = ((parts[8]+parts[9])+(parts[10]+parts[11]))
               + ((parts[12]+parts[13])+(parts[14]+parts[15])) + fc2b0;
    extl[255]=f2bf(ext0); extl[511]=f2bf(ext1);
  }
  __syncthreads();

  // ===== flush TOut / Ext_list from LDS =====
  for(int p=tid; p<496; p+=512){
    int b = (p>=248) ? 1 : 0;
    int i2 = p - b*248 + 8;
    int gb = 2*bb + b;
    out[gb*256+i2]      = bf2f(toutl[b*256+i2]);
    out[2*BT+gb*256+i2] = bf2f(extl[b*256+i2]);
  }
}

extern "C" void kernel_launch(void* const* d_in, const int* in_sizes, int n_in,
                              void* d_out, int out_size, void* d_ws, size_t ws_size,
                              hipStream_t stream)
{
  const float* in   = (const float*)d_in[0];
  const float* Wih  = (const float*)d_in[1];
  const float* Whh  = (const float*)d_in[2];
  const float* bih  = (const float*)d_in[3];
  const float* bhh  = (const float*)d_in[4];
  const float* fc1w = (const float*)d_in[5];
  const float* fc1b = (const float*)d_in[6];
  const float* fc2w = (const float*)d_in[7];
  const float* fc2b = (const float*)d_in[8];
  const float* i1w  = (const float*)d_in[9];
  const float* i1b  = (const float*)d_in[10];
  const float* i3w  = (const float*)d_in[11];
  const float* i3b  = (const float*)d_in[12];
  const float* scw  = (const float*)d_in[13];
  const float* zw   = (const float*)d_in[14];
  float* out = (float*)d_out;

  k_seq<<<dim3(256), dim3(512), 0, stream>>>(in, Wih, Whh, bih, bhh,
                                             fc1w, fc1b, fc2w, fc2b,
                                             i1w, i1b, i3w, i3b, scw, zw, out);
}

// Round 9
// 968.154 us; speedup vs baseline: 1.5021x; 1.0797x over previous
//
#include <hip/hip_runtime.h>

#define BT   (512*256)
// hbuf (bytes): zeros @0..127, pad, b0 h @192..319, b1 h @320..447
// HB0b/HB1b chosen ==64 (mod 128): h lines land on banks 16-31 for the a0
// read / 0-15 for a1, opposite the zero-lane banks -> max 2-way (free).
#define HB0b 192
#define HB1b 320
#define HLENb 448
#define LOG2E 1.44269504088896f

using short8  = __attribute__((ext_vector_type(8))) short;
using floatx4 = __attribute__((ext_vector_type(4))) float;
using int4v   = __attribute__((ext_vector_type(4))) int;
using ushort4v= __attribute__((ext_vector_type(4))) unsigned short;

__device__ inline unsigned short f2bf(float f){
  unsigned int u = __float_as_uint(f);
  u += 0x7FFFu + ((u >> 16) & 1u);          // RNE
  return (unsigned short)(u >> 16);
}
__device__ inline float bf2f(unsigned short u){
  return __uint_as_float(((unsigned int)u) << 16);
}
__device__ inline float rcpf(float x){ return __builtin_amdgcn_rcpf(x); }
__device__ inline float ex2(float x){ return __builtin_amdgcn_exp2f(x); }

// RE-BASELINE ROUND: byte-identical revert to the round-1 kernel (969us).
// r7/r8 post-mortem: conflicts are NOT on the critical path (r7 1.75e7 vs r8
// 3.38e7 at equal time), yet r8 (HB1b=336 + ln<32 store predication only)
// lost 76us vs r1 with LOWER conflicts and LOWER VALUBusy. Either the
// exec-masked DS store stalls the in-order DS queue, or cross-session
// variance is ~8%. This exact revert disambiguates: ~969 -> r8's edits were
// harmful, r1 base stands; ~1045 -> variance band, structure is at its floor.
__global__ __launch_bounds__(512,1) void k_seq(
    const float* __restrict__ in,
    const float* __restrict__ Wih,  const float* __restrict__ Whh,
    const float* __restrict__ bih,  const float* __restrict__ bhh,
    const float* __restrict__ fc1w, const float* __restrict__ fc1b,
    const float* __restrict__ fc2w, const float* __restrict__ fc2b,
    const float* __restrict__ i1w,  const float* __restrict__ i1b,
    const float* __restrict__ i3w,  const float* __restrict__ i3b,
    const float* __restrict__ scw,  const float* __restrict__ zonew,
    float* __restrict__ out)
{
  __shared__ __align__(16) signed char hbuf[2][HLENb];     // i8 h + zero region
  __shared__ __align__(16) float scratch[640];             // int-module weights
  __shared__ __align__(8)  unsigned short toutl[512];      // bf16 TOut history [b][256]
  __shared__ __align__(8)  unsigned short extl[512];       // bf16 Ext results [b][256]
  __shared__ __align__(16) unsigned short exl[2048];       // bf16 Ext_X cols [b*256+t][4]
  __shared__ float t0l[512];                               // T0 f32
  __shared__ float hvitl[512];                             // HVAC + int_all f32
  __shared__ __align__(16) float parts[16];                // fc2 partials [b][wv]

  const int tid = threadIdx.x;
  const int wv  = tid >> 6;             // 0..7
  const int ln  = tid & 63;
  const int l15 = ln & 15;
  const int quad= ln >> 4;
  const int bb  = blockIdx.x;

  // ---- init: stage per-block tables ----
  {
    int b=tid>>8, tt=tid&255;
    const float* row = in + (2*bb+b)*1792 + tt*7;
    t0l[tid] = row[0];
    exl[tid*4+0]=f2bf(row[1]); exl[tid*4+1]=f2bf(row[2]);
    exl[tid*4+2]=f2bf(row[3]); exl[tid*4+3]=f2bf(row[4]);
  }
  for(int p=tid; p<2*HLENb; p+=512) ((signed char*)hbuf)[p]=0;
  if(tid<16) toutl[(tid>>3)*256+(tid&7)] = f2bf(in[(2*bb+(tid>>3))*1792+(tid&7)*7]);
  float* lw4 = scratch;
  float* l3  = scratch + 512;
  if(tid<128){
    lw4[tid*4+0]=i1w[tid*3+0]; lw4[tid*4+1]=i1w[tid*3+1];
    lw4[tid*4+2]=i1w[tid*3+2]; lw4[tid*4+3]=i1b[tid];
    l3[tid]=i3w[tid];
  }
  __syncthreads();
  if(tid<256) hbuf[0][((tid>>7)? HB1b:HB0b) + (tid&127)] = 127;   // h=1.0 -> q=127

  // ---- fused int module (one (b,t) per thread) ----
  {
    const float b30=i3b[0], sc0=scw[0];
    int b=tid>>8, t=tid&255;
    const float* row = in + (2*bb+b)*1792 + t*7;
    float x0=row[3],x1=row[4],x2=row[5], acc=0.f;
    #pragma unroll 8
    for(int j=0;j<128;j++){
      float r=fmaxf(lw4[j*4]*x0+lw4[j*4+1]*x1+lw4[j*4+2]*x2+lw4[j*4+3],0.f);
      acc += r*l3[j];
    }
    float v = rcpf(1.f+__expf(-(acc+b30)))*sc0;
    float itv = (t<8)?0.f:v;
    int gb = 2*bb+b;
    hvitl[tid] = row[6] + itv;
    out[3*BT+gb*256+t]=itv;              // Int_list
    out[BT+gb*256+t]=row[6];             // HVAC_list
    if(t<8){ out[gb*256+t]=row[0]; out[2*BT+gb*256+t]=0.f; }
  }

  // ---- i8 weight quantization (per-row scale) into VGPRs ----
  int4v wq[4][2];        // [gate][K-chunk], rows n = 128g + 16wv + l15
  float dq[4];
  short8 xfr[4];         // W_ih bf16 (pre-scaled by log2e), K=32 pad (5 valid)
  float  bsum[4];
  #pragma unroll
  for(int g=0;g<4;g++){
    int n = 128*g + 16*wv + l15;
    bsum[g] = (bih[n]+bhh[n])*LOG2E;
    const float* wr = Whh + n*128;
    float mx = 1e-20f;
    for(int j=0;j<128;j++) mx = fmaxf(mx, fabsf(wr[j]));
    float qs = 127.f/mx;
    dq[g] = mx * (LOG2E/16129.f);        // log2e/127^2
    #pragma unroll
    for(int c=0;c<2;c++){
      int4v v4;
      #pragma unroll
      for(int d=0;d<4;d++){
        int pk=0;
        #pragma unroll
        for(int bq=0;bq<4;bq++){
          int kk = c*64 + quad*16 + d*4 + bq;
          int q = __float2int_rn(wr[kk]*qs);
          pk |= (q & 255) << (8*bq);
        }
        v4[d]=pk;
      }
      wq[g][c]=v4;
    }
    short8 f;
    #pragma unroll
    for(int j=0;j<8;j++){ int kk=quad*8+j; f[j]=(short)f2bf(kk<5?Wih[n*5+kk]*LOG2E:0.f); }
    xfr[g]=f;
  }
  int4v fq[2]; float dqf;                // fc1 i8 (NOT log2e-scaled), row n2 = 16wv + l15
  {
    int n2 = 16*wv + l15;
    const float* fr = fc1w + n2*128;
    float mx = 1e-20f;
    for(int j=0;j<128;j++) mx = fmaxf(mx, fabsf(fr[j]));
    float qs = 127.f/mx;
    dqf = mx * (1.f/16129.f);
    #pragma unroll
    for(int c=0;c<2;c++){
      int4v v4;
      #pragma unroll
      for(int d=0;d<4;d++){
        int pk=0;
        #pragma unroll
        for(int bq=0;bq<4;bq++){
          int kk = c*64 + quad*16 + d*4 + bq;
          int q = __float2int_rn(fr[kk]*qs);
          pk |= (q & 255) << (8*bq);
        }
        v4[d]=pk;
      }
      fq[c]=v4;
    }
  }

  // ---- per-lane persistent scalars ----
  const int  u     = 16*wv + l15;           // this lane's unit
  const int  bm    = quad & 1;              // this lane's batch (quads 2/3 dup)
  const int  arow  = ((l15&3)==0) ? (((l15>>2)&1)? HB1b : HB0b) : 0;  // 0 = zero region
  const int  aoff  = arow + quad*16;
  const int  hwoff = (bm? HB1b:HB0b) + u;
  const int  bpa0  = ((quad&1)<<7) | (l15<<2);  // bpermute byte addr, k<4
  const int  bpa1  = bpa0 + 64;                 // k>=4
  const float fb    = fc1b[u];
  const float fcw_u = fc2w[u];
  const float fc2b0 = fc2b[0];
  const float zwv   = zonew[0];
  const floatx4 ZV  = {0.f,0.f,0.f,0.f};
  const int4v   ZI  = {0,0,0,0};
  const short8  Z8  = 0;
  float E0 = in[(2*bb)*1792 + 56];          // E in EVERY lane's registers
  float E1 = in[(2*bb+1)*1792 + 56];
  float c0 = 1.f;
  __syncthreads();

  #pragma unroll 1
  for(int i=8;i<256;i++){
    // ===== phase A: deferred E-update (i-1), TOut, embed, x-MFMA+bpermute =====
    if(i>8){
      floatx4 pa=*(const floatx4*)&parts[0];
      floatx4 pb=*(const floatx4*)&parts[4];
      floatx4 pc=*(const floatx4*)&parts[8];
      floatx4 pd=*(const floatx4*)&parts[12];
      float ext0=((pa[0]+pa[1])+(pa[2]+pa[3]))+((pb[0]+pb[1])+(pb[2]+pb[3]))+fc2b0;
      float ext1=((pc[0]+pc[1])+(pc[2]+pc[3]))+((pd[0]+pd[1])+(pd[2]+pd[3]))+fc2b0;
      int ip = i-1;
      float tot0 = ext0 + hvitl[ip];
      float tot1 = ext1 + hvitl[256+ip];
      if(ip<128){
        float ratio=(float)ip*0.0078125f;
        E0 = ratio*t0l[ip]     + (1.f-ratio)*E0 + tot0*zwv;
        E1 = ratio*t0l[256+ip] + (1.f-ratio)*E1 + tot1*zwv;
      } else {
        E0 += tot0*zwv;
        E1 += tot1*zwv;
      }
      if(tid==0){ extl[ip]=f2bf(ext0); extl[256+ip]=f2bf(ext1); }
    }
    if(tid==0){ toutl[i]=f2bf(E0); toutl[256+i]=f2bf(E1); }   // TOut[:,i]=E
    float xv[8][4];                        // x-gates, f32, register-resident
    {
      short8 ea = Z8;
      if(quad==0){
        int bE=l15>>3, kk=l15&7, p=i-7+kk;
        float tos = (p==i) ? (bE? E1:E0) : bf2f(toutl[bE*256+p]);
        float tmix;
        if(i<128){
          float ratio=(float)i*0.0078125f;
          tmix = t0l[bE*256+p]*ratio + tos*(1.f-ratio);
        } else tmix = tos;
        ea[0]=(short)f2bf(tmix);
        ushort4v e4 = *(const ushort4v*)&exl[(bE*256+p)*4];
        ea[1]=(short)e4[0]; ea[2]=(short)e4[1];
        ea[3]=(short)e4[2]; ea[4]=(short)e4[3];
      }
      #pragma unroll
      for(int g=0;g<4;g++){
        floatx4 z=__builtin_amdgcn_mfma_f32_16x16x32_bf16(ea, xfr[g], ZV,0,0,0);
        #pragma unroll
        for(int r=0;r<4;r++){
          int zi = __float_as_int(z[r]+bsum[g]);
          xv[r][g]   = __int_as_float(__builtin_amdgcn_ds_bpermute(bpa0, zi));
          xv[r+4][g] = __int_as_float(__builtin_amdgcn_ds_bpermute(bpa1, zi));
        }
      }
    }
    // NO barrier here: hbuf/parts already fenced by prev iter's barriers.

    // ===== 8 inner LSTM steps: 8 i8 MFMAs/wave, single nonlin chain =====
    #pragma unroll
    for(int k=0;k<8;k++){
      float xv0=xv[k][0];
      float xv1=xv[k][1];
      float xv2=xv[k][2];
      float xv3=xv[k][3];
      const signed char* hb = &hbuf[k&1][0];
      int4v a0 = *(const int4v*)(hb + aoff);        // K 0..63
      int4v a1 = *(const int4v*)(hb + aoff + 64);   // K 64..127
      int4v acc[4];
      #pragma unroll
      for(int g=0;g<4;g++){
        int4v z = __builtin_amdgcn_mfma_i32_16x16x64_i8(a0, wq[g][0], ZI,0,0,0);
        z = __builtin_amdgcn_mfma_i32_16x16x64_i8(a1, wq[g][1], z,0,0,0);
        acc[g]=z;
      }
      float gi=fmaf((float)acc[0][0],dq[0],xv0);    // all in log2e domain
      float gf=fmaf((float)acc[1][0],dq[1],xv1);
      float gg=fmaf((float)acc[2][0],dq[2],xv2);
      float go=fmaf((float)acc[3][0],dq[3],xv3);
      float ef =ex2(-gf);                           // bare v_exp
      float egi=ex2(-gi);
      float egg=ex2(-2.f*gg);
      float sf = rcpf(1.f+ef);
      float itn=(1.f-egg)*rcpf((1.f+egi)*(1.f+egg));
      c0 = sf*c0 + itn;
      float ego=ex2(-go);
      float ec =ex2(-2.8853900818f*c0);             // c unscaled: x2log2e
      float hv2=(1.f-ec)*rcpf((1.f+ego)*(1.f+ec));
      int q = __float2int_rn(hv2*127.f);            // |h|<1 -> |q|<=127
      hbuf[(k+1)&1][hwoff] = (signed char)q;        // quads 2/3 dup same value
      __syncthreads();
    }

    // ===== fc1 (i8) + within-quad fc2 reduce (both batches in parallel) =====
    {
      const signed char* hb = &hbuf[0][0];
      int4v a0 = *(const int4v*)(hb + aoff);
      int4v a1 = *(const int4v*)(hb + aoff + 64);
      int4v z = __builtin_amdgcn_mfma_i32_16x16x64_i8(a0, fq[0], ZI,0,0,0);
      z = __builtin_amdgcn_mfma_i32_16x16x64_i8(a1, fq[1], z,0,0,0);
      float fv = (float)z[0]*dqf + fb;
      float pv = fmaxf(fv,0.f)*fcw_u;
      pv += __shfl_xor(pv, 1, 64);       // xor{1,2,4,8} stays within quad:
      pv += __shfl_xor(pv, 2, 64);       // quad0/2 reduce batch0, quad1/3 batch1
      pv += __shfl_xor(pv, 4, 64);
      pv += __shfl_xor(pv, 8, 64);
      if(ln==0)       parts[wv]   = pv;  // batch0 block: parts[0..7]
      else if(ln==16) parts[8+wv] = pv;  // batch1 block: parts[8..15]
    }
    __syncthreads();
  }

  // ===== tail: ext(255) from last fc =====
  if(tid==0){
    float ext0 = ((parts[0]+parts[1])+(parts[2]+parts[3]))
               + ((parts[4]+parts[5])+(parts[6]+parts[7])) + fc2b0;
    float ext1 = ((parts[8]+parts[9])+(parts[10]+parts[11]))
               + ((parts[12]+parts[13])+(parts[14]+parts[15])) + fc2b0;
    extl[255]=f2bf(ext0); extl[511]=f2bf(ext1);
  }
  __syncthreads();

  // ===== flush TOut / Ext_list from LDS =====
  for(int p=tid; p<496; p+=512){
    int b = (p>=248) ? 1 : 0;
    int i2 = p - b*248 + 8;
    int gb = 2*bb + b;
    out[gb*256+i2]      = bf2f(toutl[b*256+i2]);
    out[2*BT+gb*256+i2] = bf2f(extl[b*256+i2]);
  }
}

extern "C" void kernel_launch(void* const* d_in, const int* in_sizes, int n_in,
                              void* d_out, int out_size, void* d_ws, size_t ws_size,
                              hipStream_t stream)
{
  const float* in   = (const float*)d_in[0];
  const float* Wih  = (const float*)d_in[1];
  const float* Whh  = (const float*)d_in[2];
  const float* bih  = (const float*)d_in[3];
  const float* bhh  = (const float*)d_in[4];
  const float* fc1w = (const float*)d_in[5];
  const float* fc1b = (const float*)d_in[6];
  const float* fc2w = (const float*)d_in[7];
  const float* fc2b = (const float*)d_in[8];
  const float* i1w  = (const float*)d_in[9];
  const float* i1b  = (const float*)d_in[10];
  const float* i3w  = (const float*)d_in[11];
  const float* i3b  = (const float*)d_in[12];
  const float* scw  = (const float*)d_in[13];
  const float* zw   = (const float*)d_in[14];
  float* out = (float*)d_out;

  k_seq<<<dim3(256), dim3(512), 0, stream>>>(in, Wih, Whh, bih, bhh,
                                             fc1w, fc1b, fc2w, fc2b,
                                             i1w, i1b, i3w, i3b, scw, zw, out);
}